// Round 9
// baseline (1050.120 us; speedup 1.0000x reference)
//
#include <hip/hip_runtime.h>

typedef unsigned short u16;
typedef u16 u16x8 __attribute__((ext_vector_type(8)));
typedef __bf16 bf16x8 __attribute__((ext_vector_type(8)));
typedef float f32x4 __attribute__((ext_vector_type(4)));

#define DEV __device__ __forceinline__
#define MFMA16 __builtin_amdgcn_mfma_f32_16x16x32_bf16

constexpr int Bb = 2, Nctx = 2048, Dm = 512, Hh = 8, Dh = 512, Ff = 4096;
constexpr int Mrows = Bb * Nctx;  // 4096

DEV float b2f(u16 u) { unsigned int i = ((unsigned int)u) << 16; return __builtin_bit_cast(float, i); }
DEV u16 f2b(float f) {
  unsigned int x = __builtin_bit_cast(unsigned int, f);
  return (u16)((x + 0x7FFFu + ((x >> 16) & 1u)) >> 16);
}
DEV bf16x8 ld8(const u16* p) { return __builtin_bit_cast(bf16x8, *(const u16x8*)p); }

// async global->LDS, 16B per lane. LDS dest must be wave-uniform base + lane*16.
DEV void gload16(const u16* g, u16* l) {
#if defined(__has_builtin) && __has_builtin(__builtin_amdgcn_global_load_lds)
  __builtin_amdgcn_global_load_lds((const __attribute__((address_space(1))) void*)(g),
                                   (__attribute__((address_space(3))) void*)(l), 16, 0, 0);
#else
  *(u16x8*)l = *(const u16x8*)g;
#endif
}

// ---------------- f32 -> bf16 convert ----------------
__global__ void convert_k(const float* __restrict__ in, u16* __restrict__ out, int n8) {
  int idx = blockIdx.x * 256 + threadIdx.x;
  if (idx >= n8) return;
  size_t e0 = (size_t)idx * 8;
  f32x4 a = *(const f32x4*)(in + e0);
  f32x4 b = *(const f32x4*)(in + e0 + 4);
  u16x8 o;
  #pragma unroll
  for (int i = 0; i < 4; ++i) { o[i] = f2b(a[i]); o[4 + i] = f2b(b[i]); }
  *(u16x8*)(out + e0) = o;
}

// ---------------- transpose + convert: out_bf16[c][r] = in_f32[r][c] ----------------
__global__ void transpose_k(const float* __restrict__ in, u16* __restrict__ out,
                            int rows, int cols) {
  __shared__ float tile[32][33];
  int bx = blockIdx.x * 32, by = blockIdx.y * 32;
  int tx = threadIdx.x, ty = threadIdx.y;
  #pragma unroll
  for (int i = ty; i < 32; i += 8)
    tile[i][tx] = in[(size_t)(by + i) * cols + bx + tx];
  __syncthreads();
  #pragma unroll
  for (int i = ty; i < 32; i += 8)
    out[(size_t)(bx + i) * rows + by + tx] = f2b(tile[tx][i]);
}

// ---------------- batched V transpose: Vt[bh][d][n] = V[b*N+n][h*Dh+d] ----------------
__global__ void vtrans_k(const u16* __restrict__ V, u16* __restrict__ Vt) {
  __shared__ u16 tile[32][33];
  int z = blockIdx.z;  // b*8+h
  int b = z >> 3, h = z & 7;
  int n0 = blockIdx.x * 32, d0 = blockIdx.y * 32;
  int tx = threadIdx.x, ty = threadIdx.y;
  #pragma unroll
  for (int i = ty; i < 32; i += 8)
    tile[i][tx] = V[((size_t)(b * Nctx + n0 + i)) * Ff + h * Dh + d0 + tx];
  __syncthreads();
  #pragma unroll
  for (int i = ty; i < 32; i += 8)
    Vt[((size_t)(z * Dh + d0 + i)) * Nctx + n0 + tx] = tile[tx][i];
}

// ------- GEMM 128x128 tile, BK=32, global_load_lds staging, 4 waves 2x2 -------
// MODE: 0 plain->bf16, 1 rope->bf16, 2 bias->bf16, 3 bias->f32
template <int MODE>
__launch_bounds__(256, 4)
__global__ void gemm2_k(const u16* __restrict__ A, const u16* __restrict__ BT,
                        void* __restrict__ Cout, const float* __restrict__ bias,
                        const float* __restrict__ cs, const float* __restrict__ sn,
                        int Ndim, int Kdim) {
  __shared__ u16 sA[128 * 32];
  __shared__ u16 sB[128 * 32];
  const int tid = threadIdx.x;
  const int wave = tid >> 6, lane = tid & 63, quad = lane >> 4, l16 = lane & 15;
  const int wy = wave >> 1, wx = wave & 1;
  const int m0 = blockIdx.y * 128, n0 = blockIdx.x * 128;
  f32x4 acc[4][4];
  #pragma unroll
  for (int i = 0; i < 4; ++i)
    #pragma unroll
    for (int j = 0; j < 4; ++j)
      #pragma unroll
      for (int r = 0; r < 4; ++r) acc[i][j][r] = 0.f;
  const int srow = tid >> 2, sch = (tid & 3) * 8;  // LDS flat = tid*16B (wave-linear)
  const u16* agp = A + (size_t)(m0 + srow) * Kdim + sch;
  const u16* bgp = BT + (size_t)(n0 + srow) * Kdim + sch;
  for (int k0 = 0; k0 < Kdim; k0 += 32) {
    __syncthreads();
    gload16(agp + k0, &sA[srow * 32 + sch]);
    gload16(agp + (size_t)64 * Kdim + k0, &sA[(64 + srow) * 32 + sch]);
    gload16(bgp + k0, &sB[srow * 32 + sch]);
    gload16(bgp + (size_t)64 * Kdim + k0, &sB[(64 + srow) * 32 + sch]);
    __syncthreads();
    bf16x8 af[4], bf[4];
    #pragma unroll
    for (int t = 0; t < 4; ++t) af[t] = ld8(&sA[(wy * 64 + t * 16 + l16) * 32 + quad * 8]);
    #pragma unroll
    for (int t = 0; t < 4; ++t) bf[t] = ld8(&sB[(wx * 64 + t * 16 + l16) * 32 + quad * 8]);
    #pragma unroll
    for (int i = 0; i < 4; ++i)
      #pragma unroll
      for (int j = 0; j < 4; ++j)
        acc[i][j] = MFMA16(af[i], bf[j], acc[i][j], 0, 0, 0);
  }
  #pragma unroll
  for (int i = 0; i < 4; ++i) {
    #pragma unroll
    for (int j = 0; j < 4; ++j) {
      int col = n0 + wx * 64 + j * 16 + l16;
      float badd = (MODE == 2 || MODE == 3) ? bias[col] : 0.f;
      #pragma unroll
      for (int r = 0; r < 4; ++r) {
        int row = m0 + wy * 64 + i * 16 + quad * 4 + r;  // C: col=lane&15, row=quad*4+reg
        float v = acc[i][j][r] + badd;
        if (MODE == 1) {  // fused RoPE: pairs (col even, col odd) across lane^1
          float vp = __shfl_xor(v, 1);
          int n = row & (Nctx - 1);
          float c = cs[(size_t)n * Ff + col];
          float s = sn[(size_t)n * Ff + col];
          v = (l16 & 1) ? (v * c + vp * s) : (v * c - vp * s);
        }
        if (MODE == 3) ((float*)Cout)[(size_t)row * Ndim + col] = v;
        else           ((u16*)Cout)[(size_t)row * Ndim + col] = f2b(v);
      }
    }
  }
}

// ---------------- flash attention v6 (causal, unscaled) ----------------
// kt=32. K staged in LDS (async DMA, rotated chunks). V fragments prefetched
// global->registers (wave-private 128-dh slice; 4 frags after barrier1 hidden
// under QK^T+softmax, 4 after barrier2 before stageK so the DMA stays in
// flight through PV). lrun is a PER-LANE partial; the single cross-lane
// reduction happens at the end (v4/v5 double-reduced -> /16 outputs).
__launch_bounds__(256, 2)
__global__ void attn_k(const u16* __restrict__ Q, const u16* __restrict__ K,
                       const u16* __restrict__ Vt, u16* __restrict__ Yp) {
  __shared__ u16 sK[32 * 512];   // [key][dh], phys chunk16 = (chunk+key)&63
  __shared__ u16 sP[64 * 40];    // P tile, stride 40
  __shared__ float sAl[64];
  __shared__ float sL[64];
  const int idx = blockIdx.x;
  const int second = idx >> 8;               // 0 | 1
  const int bh = (idx & 7) | (second << 3);  // XCD-affine
  const int qt5 = (idx >> 3) & 31;
  const int qt = second ? qt5 : 31 - qt5;    // complementary work pairing
  const int b = bh >> 3, h = bh & 7;
  const int q0 = qt * 64;
  const int wave = threadIdx.x >> 6, lane = threadIdx.x & 63;
  const int quad = lane >> 4, l16 = lane & 15;
  const int mq = q0 + wave * 16;  // QK^T rows for this wave
  const int wd = wave * 128;      // PV dh-slice for this wave

  bf16x8 qf[16];
  {
    const u16* qp = Q + ((size_t)(b * Nctx + mq + l16)) * Ff + h * Dh + quad * 8;
    #pragma unroll
    for (int i = 0; i < 16; ++i) qf[i] = ld8(qp + i * 32);
  }
  f32x4 acc[4][8];
  #pragma unroll
  for (int g = 0; g < 4; ++g)
    #pragma unroll
    for (int t = 0; t < 8; ++t)
      #pragma unroll
      for (int r = 0; r < 4; ++r) acc[g][t][r] = 0.f;
  float mrun[4], lrun[4];
  #pragma unroll
  for (int r = 0; r < 4; ++r) { mrun[r] = -__builtin_inff(); lrun[r] = 0.f; }

  auto stageK = [&](int j0) {  // 32 rows; wave stages rows wave*8..+7
    #pragma unroll
    for (int it = 0; it < 8; ++it) {
      int row = wave * 8 + it;
      const u16* gp = K + ((size_t)(b * Nctx + j0 + row)) * Ff + h * Dh + (((lane - row) & 63) * 8);
      gload16(gp, &sK[row * 512 + lane * 8]);
    }
  };
  // V B-frag pointer: B[k=quad*8+j][n=l16] = Vt[wd + t*16 + l16][j0 + quad*8 + j]
  const u16* vbase = Vt + ((size_t)(bh * Dh + wd + l16)) * Nctx + quad * 8;

  const int njt = 2 * qt + 2;
  stageK(0);
  for (int jt = 0; jt < njt; ++jt) {
    const int j0 = jt * 32;
    __syncthreads();  // K(jt) DMA drained (vmcnt0 before barrier); prev sP reads done
    // V prefetch, first half: latency hidden by QK^T + softmax below
    bf16x8 vf0[4];
    #pragma unroll
    for (int t = 0; t < 4; ++t)
      vf0[t] = ld8(vbase + (size_t)(t * 16) * Nctx + j0);
    // --- QK^T: 16 q-rows/wave x 32 keys ---
    f32x4 s[2];
    #pragma unroll
    for (int kg = 0; kg < 2; ++kg)
      #pragma unroll
      for (int r = 0; r < 4; ++r) s[kg][r] = 0.f;
    #pragma unroll
    for (int kk = 0; kk < 16; ++kk) {
      #pragma unroll
      for (int kg = 0; kg < 2; ++kg) {
        int key = kg * 16 + l16;
        bf16x8 bfr = ld8(&sK[key * 512 + (((kk * 4 + quad + key) & 63) * 8)]);
        s[kg] = MFMA16(qf[kk], bfr, s[kg], 0, 0, 0);
      }
    }
    // --- online softmax (mask unconditional; off-diag tiles compare false) ---
    float p0a[4], p1a[4], alpha[4];
    #pragma unroll
    for (int r = 0; r < 4; ++r) {
      int qrow = mq + quad * 4 + r;
      float sv0 = (j0 + l16 > qrow) ? -__builtin_inff() : s[0][r];
      float sv1 = (j0 + 16 + l16 > qrow) ? -__builtin_inff() : s[1][r];
      float mx = fmaxf(sv0, sv1);
      mx = fmaxf(mx, __shfl_xor(mx, 1));
      mx = fmaxf(mx, __shfl_xor(mx, 2));
      mx = fmaxf(mx, __shfl_xor(mx, 4));
      mx = fmaxf(mx, __shfl_xor(mx, 8));
      float mnew = fmaxf(mrun[r], mx);
      float a = __expf(mrun[r] - mnew);
      float p0 = __expf(sv0 - mnew);
      float p1 = __expf(sv1 - mnew);
      // lrun stays a PER-LANE partial (this lane's 2 keys). The one and only
      // cross-lane sum happens in the epilogue. (R7/R8 bug: butterfly here AND
      // there -> sL = 16x -> outputs /16.)
      lrun[r] = lrun[r] * a + (p0 + p1);
      mrun[r] = mnew;
      alpha[r] = a;
      p0a[r] = p0; p1a[r] = p1;
    }
    #pragma unroll
    for (int r = 0; r < 4; ++r) {
      sP[(wave * 16 + quad * 4 + r) * 40 + l16]      = f2b(p0a[r]);
      sP[(wave * 16 + quad * 4 + r) * 40 + 16 + l16] = f2b(p1a[r]);
      if (l16 == 0) sAl[wave * 16 + quad * 4 + r] = alpha[r];
    }
    __syncthreads();  // sP/sAl visible; all waves done reading sK(jt); vf0 arrived
    // V prefetch, second half (before stageK so its wait leaves DMAs in flight)
    bf16x8 vf1[4];
    #pragma unroll
    for (int t = 0; t < 4; ++t)
      vf1[t] = ld8(vbase + (size_t)((4 + t) * 16) * Nctx + j0);
    if (jt + 1 < njt) stageK(j0 + 32);  // async DMA into sK; overlaps PV below
    // --- PV from registers (wave-private dh slice), K=32 in one MFMA step ---
    {
      float alr[4][4];
      #pragma unroll
      for (int g = 0; g < 4; ++g)
        #pragma unroll
        for (int r = 0; r < 4; ++r) alr[g][r] = sAl[g * 16 + quad * 4 + r];
      #pragma unroll
      for (int g = 0; g < 4; ++g)
        #pragma unroll
        for (int t = 0; t < 8; ++t)
          #pragma unroll
          for (int r = 0; r < 4; ++r) acc[g][t][r] *= alr[g][r];
      bf16x8 pf[4];
      #pragma unroll
      for (int g = 0; g < 4; ++g)
        pf[g] = ld8(&sP[(g * 16 + l16) * 40 + quad * 8]);
      #pragma unroll
      for (int t = 0; t < 4; ++t)
        #pragma unroll
        for (int g = 0; g < 4; ++g) acc[g][t] = MFMA16(pf[g], vf0[t], acc[g][t], 0, 0, 0);
      #pragma unroll
      for (int t = 0; t < 4; ++t)
        #pragma unroll
        for (int g = 0; g < 4; ++g) acc[g][4 + t] = MFMA16(pf[g], vf1[t], acc[g][4 + t], 0, 0, 0);
    }
  }
  // single cross-lane row-sum of the per-lane partials -> sL
  #pragma unroll
  for (int r = 0; r < 4; ++r) {
    float l = lrun[r];
    l += __shfl_xor(l, 1);
    l += __shfl_xor(l, 2);
    l += __shfl_xor(l, 4);
    l += __shfl_xor(l, 8);
    if (l16 == 0) sL[wave * 16 + quad * 4 + r] = l;
  }
  __syncthreads();
  #pragma unroll
  for (int g = 0; g < 4; ++g) {
    float inv[4];
    #pragma unroll
    for (int r = 0; r < 4; ++r) inv[r] = 1.f / sL[g * 16 + quad * 4 + r];
    #pragma unroll
    for (int t = 0; t < 8; ++t)
      #pragma unroll
      for (int r = 0; r < 4; ++r)
        Yp[((size_t)bh * Nctx + q0 + g * 16 + quad * 4 + r) * Dh + wd + t * 16 + l16] =
            f2b(acc[g][t][r] * inv[r]);
  }
}

// ---------------- head-sum + QuickGELU -> bf16 ----------------
__global__ void sumheads_k(const u16* __restrict__ Yp, u16* __restrict__ Ys) {
  size_t idx = (size_t)blockIdx.x * 256 + threadIdx.x;
  size_t e0 = idx * 8;
  int b = (int)(e0 >> 20);
  size_t rem = e0 & ((1u << 20) - 1);
  float s[8];
  #pragma unroll
  for (int e = 0; e < 8; ++e) s[e] = 0.f;
  #pragma unroll
  for (int h = 0; h < Hh; ++h) {
    u16x8 v = *(const u16x8*)&Yp[((size_t)(b * Hh + h) << 20) + rem];
    #pragma unroll
    for (int e = 0; e < 8; ++e) s[e] += b2f(v[e]);
  }
  u16x8 o;
  #pragma unroll
  for (int e = 0; e < 8; ++e) {
    float g = s[e] / (1.f + __expf(-1.702f * s[e]));
    o[e] = f2b(g);
  }
  *(u16x8*)&Ys[e0] = o;
}

extern "C" void kernel_launch(void* const* d_in, const int* in_sizes, int n_in,
                              void* d_out, int out_size, void* d_ws, size_t ws_size,
                              hipStream_t stream) {
  const float* x  = (const float*)d_in[0];
  const float* cs = (const float*)d_in[1];
  const float* sn = (const float*)d_in[2];
  int wbase = 4;                        // target_mask (bool tril) at idx 3, hard-coded
  if (n_in == 9) wbase = 3;
  if (wbase + 3 < n_in && in_sizes[wbase + 3] != 4096) wbase = (wbase == 4) ? 3 : 4;
  const float* Wq = (const float*)d_in[wbase + 0];
  const float* Wk = (const float*)d_in[wbase + 1];
  const float* Wv = (const float*)d_in[wbase + 2];
  const float* bv = (const float*)d_in[wbase + 3];
  const float* Wo = (const float*)d_in[wbase + 4];
  const float* bo = (const float*)d_in[wbase + 5];

  // ws layout (132.5 MiB), with aliasing:
  //  [0,32M): WqT@0, WkT@4M, WvT@8M, xb@12M  -> later reused as Vt
  //  [32,64M): Qb   [64,96M): Kb   [96,128M): Vb -> later reused as Yp
  //  [128M,+0.5M): WoT   [+0.5M,+4.5M): Ys
  char* ws = (char*)d_ws;
  const size_t MiB = 1ull << 20;
  u16* WqT = (u16*)(ws + 0 * MiB);
  u16* WkT = (u16*)(ws + 4 * MiB);
  u16* WvT = (u16*)(ws + 8 * MiB);
  u16* xb  = (u16*)(ws + 12 * MiB);
  u16* Vt  = (u16*)(ws + 0 * MiB);    // alias: weights/xb dead after QKV gemms
  u16* Qb  = (u16*)(ws + 32 * MiB);
  u16* Kb  = (u16*)(ws + 64 * MiB);
  u16* Vb  = (u16*)(ws + 96 * MiB);
  u16* Yp  = Vb;                      // alias: Vb dead after vtrans
  u16* WoT = (u16*)(ws + 128 * MiB);
  u16* Ys  = (u16*)(ws + 128 * MiB + 512 * 1024);

  dim3 tb(32, 8);
  transpose_k<<<dim3(Ff / 32, Dm / 32), tb, 0, stream>>>(Wq, WqT, Dm, Ff);
  transpose_k<<<dim3(Ff / 32, Dm / 32), tb, 0, stream>>>(Wk, WkT, Dm, Ff);
  transpose_k<<<dim3(Ff / 32, Dm / 32), tb, 0, stream>>>(Wv, WvT, Dm, Ff);
  transpose_k<<<dim3(Dm / 32, Dm / 32), tb, 0, stream>>>(Wo, WoT, Dm, Dm);
  convert_k<<<dim3(Mrows * Dm / 8 / 256), 256, 0, stream>>>(x, xb, Mrows * Dm / 8);

  gemm2_k<1><<<dim3(Ff / 128, Mrows / 128), 256, 0, stream>>>(xb, WqT, Qb, nullptr, cs, sn, Ff, Dm);
  gemm2_k<1><<<dim3(Ff / 128, Mrows / 128), 256, 0, stream>>>(xb, WkT, Kb, nullptr, cs, sn, Ff, Dm);
  gemm2_k<2><<<dim3(Ff / 128, Mrows / 128), 256, 0, stream>>>(xb, WvT, Vb, bv, nullptr, nullptr, Ff, Dm);

  vtrans_k<<<dim3(Nctx / 32, Dh / 32, Bb * Hh), tb, 0, stream>>>(Vb, Vt);

  attn_k<<<dim3(512), 256, 0, stream>>>(Qb, Kb, Vt, Yp);

  sumheads_k<<<dim3(Mrows * Dm / 8 / 256), 256, 0, stream>>>(Yp, Ys);

  gemm2_k<3><<<dim3(Dm / 128, Mrows / 128), 256, 0, stream>>>(Ys, WoT, d_out, bo, nullptr, nullptr, Dm, Dm);
}